// Round 7
// baseline (946.312 us; speedup 1.0000x reference)
//
#include <hip/hip_runtime.h>
#include <hip/hip_cooperative_groups.h>
#include <math.h>

namespace cg = cooperative_groups;

#define NN 100000
#define NE 1200000
#define NDIFF 1000
#define CAP 48        // per-node edge bucket capacity; Poisson(12) tail at 48 ~1e-15
#define SLICE 2048    // edges per bin block
#define NQ 200        // node-range queues (SUBN nodes each); NQ*SUBN == NN
#define SUBN 500      // nodes per queue / per scatter block
#define QCAPB 32      // per-block per-queue LDS bin capacity (mean 10.2, +8sd)
#define NSH 8         // queue shards (blockIdx&7 ~ XCD) for write-combined flush
#define SQS 1024      // records per (queue,shard): mean 750, sd 27, +10sd
#define PB 1563       // persistent blocks: 1563*64 = 100032 >= NN; < 2048 co-resident

typedef short short8 __attribute__((ext_vector_type(8)));
typedef float floatx4 __attribute__((ext_vector_type(4)));
typedef float floatx2 __attribute__((ext_vector_type(2)));
typedef unsigned short ushort_t;
typedef unsigned long long ull_t;

__device__ __forceinline__ float softplusf_(float x) {
  return fmaxf(x, 0.f) + logf(1.f + __expf(-fabsf(x)));
}
__device__ __forceinline__ float sigmoidf_(float x) {
  return 1.f / (1.f + __expf(-x));
}
__device__ __forceinline__ float tanhf_fast(float x) {
  float ax = fabsf(x);
  float e = __expf(-2.f * ax);
  float t = (1.f - e) / (1.f + e);
  return x < 0.f ? -t : t;
}
__device__ __forceinline__ ushort_t f2bf(float f) {
  unsigned u = __float_as_uint(f);
  unsigned r = (u + 0x7FFFu + ((u >> 16) & 1u)) >> 16;
  return (ushort_t)r;
}
__device__ __forceinline__ float bf2f(ushort_t s) {
  return __uint_as_float(((unsigned)s) << 16);
}
// pack 8 bf16 (short8) -> 8 fp8 e4m3 bytes (uint2)
__device__ __forceinline__ uint2 bf8_to_fp8x8(short8 v) {
  float f[8];
  #pragma unroll
  for (int i = 0; i < 8; ++i) f[i] = bf2f((ushort_t)v[i]);
  int a = 0, b = 0;
  a = __builtin_amdgcn_cvt_pk_fp8_f32(f[0], f[1], a, false);
  a = __builtin_amdgcn_cvt_pk_fp8_f32(f[2], f[3], a, true);
  b = __builtin_amdgcn_cvt_pk_fp8_f32(f[4], f[5], b, false);
  b = __builtin_amdgcn_cvt_pk_fp8_f32(f[6], f[7], b, true);
  uint2 r; r.x = (unsigned)a; r.y = (unsigned)b;
  return r;
}

// ---------------- setup: fragment-major weights + wtab + diff scatter ----------------

__global__ void prep_w_kernel(const float* __restrict__ lin1_w, const float* __restrict__ lin2_w,
                              const float* __restrict__ w_ih, const float* __restrict__ w_hh,
                              const float* __restrict__ etw, const int* __restrict__ diff,
                              ushort_t* __restrict__ W1s, ushort_t* __restrict__ W2s,
                              ushort_t* __restrict__ Wcs, float* __restrict__ wtab,
                              unsigned char* __restrict__ flagb) {
  int i = blockIdx.x * 256 + threadIdx.x;  // 0..81919
  if (i < 8) wtab[i] = softplusf_(etw[i]);
  if (i < NDIFF) flagb[diff[i]] = 1;
  if (i < 32768) {
    int fi = i >> 9, lane = (i >> 3) & 63, j = i & 7;
    int s = fi >> 4, ct = fi & 15;
    int quad = lane >> 4, l15 = lane & 15;
    int col = ct * 16 + l15, k = s * 32 + quad * 8 + j;
    W1s[i] = f2bf(lin1_w[col * 128 + k]);
  } else if (i < 49152) {
    int i2 = i - 32768;
    int fi = i2 >> 9, lane = (i2 >> 3) & 63, j = i2 & 7;
    int s = fi >> 2, ct = fi & 3;
    int quad = lane >> 4, l15 = lane & 15;
    int col = ct * 16 + l15, k = s * 32 + quad * 8 + j;
    W2s[i2] = f2bf(lin2_w[col * 256 + k]);
  } else {
    int i3 = i - 49152;
    int fi = i3 >> 9, lane = (i3 >> 3) & 63, j = i3 & 7;
    int s = fi >> 4, ct = fi & 15;
    int quad = lane >> 4, l15 = lane & 15;
    int jj = ct * 16 + l15, k = s * 32 + quad * 8 + j;
    float v;
    if (jj < 128)      v = (k < 64) ? w_ih[jj * 64 + k] : w_hh[jj * 64 + (k - 64)];
    else if (jj < 192) v = (k < 64) ? w_ih[jj * 64 + k] : 0.f;
    else               v = (k < 64) ? 0.f : w_hh[(jj - 64) * 64 + (k - 64)];
    Wcs[i3] = f2bf(v);
  }
}

// ---------------- two-phase CSR build, amplification-free ----------------

__launch_bounds__(256)
__global__ void bin_kernel(const int* __restrict__ src, const int* __restrict__ dst,
                           const int* __restrict__ etype,
                           unsigned* __restrict__ gtail, ull_t* __restrict__ staging) {
  __shared__ uint2 bin[NQ][QCAPB];   // 51200 B
  __shared__ unsigned lcur[NQ];      // 800 B
  int t = threadIdx.x;
  int shard = blockIdx.x & 7;
  for (int i = t; i < NQ; i += 256) lcur[i] = 0;
  __syncthreads();
  int base = blockIdx.x * SLICE;

  uint2 rec[8];
  int qq[8];
  unsigned idx[8];
  #pragma unroll
  for (int it = 0; it < 8; ++it) {
    int e = base + it * 256 + t;
    qq[it] = -1;
    if (e < NE) {
      int d = __builtin_nontemporal_load(&dst[e]);
      int s = __builtin_nontemporal_load(&src[e]);
      int tv = __builtin_nontemporal_load(&etype[e]);
      rec[it].x = (unsigned)(s | (tv << 17));
      rec[it].y = (unsigned)d;
      int q = d / SUBN;
      qq[it] = q;
      unsigned i = atomicAdd(&lcur[q], 1u);
      idx[it] = i;
      if (i < QCAPB) bin[q][i] = rec[it];
    }
  }
  __syncthreads();
  // flush: one thread per queue -> one tail atomic + contiguous copy
  if (t < NQ) {
    unsigned c = min(lcur[t], (unsigned)QCAPB);
    if (c) {
      unsigned gb = atomicAdd(&gtail[(t * NSH + shard) * 16], c);
      ull_t* qst = staging + (size_t)(t * NSH + shard) * SQS + gb;
      const uint2* b = bin[t];
      for (unsigned i = 0; i < c; ++i)
        qst[i] = ((ull_t)b[i].y << 32) | (ull_t)b[i].x;
    }
  }
  // overflow stragglers (probability ~1e-3 per grid; correctness fallback)
  #pragma unroll
  for (int it = 0; it < 8; ++it) {
    if (qq[it] >= 0 && idx[it] >= QCAPB) {
      unsigned gb = atomicAdd(&gtail[(qq[it] * NSH + shard) * 16], 1u);
      staging[(size_t)(qq[it] * NSH + shard) * SQS + gb] =
          ((ull_t)rec[it].y << 32) | (ull_t)rec[it].x;
    }
  }
}

__launch_bounds__(512)
__global__ void scatter_kernel(const ull_t* __restrict__ staging,
                               const unsigned* __restrict__ gtail,
                               unsigned* __restrict__ cpack, int* __restrict__ csr) {
  __shared__ int cnt[SUBN];
  int t = threadIdx.x;
  int q = blockIdx.x;
  int n0 = q * SUBN;
  for (int i = t; i < SUBN; i += 512) cnt[i] = 0;
  __syncthreads();

  #pragma unroll 1
  for (int sh = 0; sh < NSH; ++sh) {
    unsigned n = gtail[(q * NSH + sh) * 16];
    const ull_t* st = staging + (size_t)(q * NSH + sh) * SQS;
    for (unsigned i = t; i < n; i += 512) {
      ull_t r = st[i];
      int d = (int)(r >> 32);
      int rank = atomicAdd(&cnt[d - n0], 1);
      csr[d * CAP + rank] = (int)(unsigned)r;
    }
  }
  __syncthreads();

  if (t < SUBN / 4) {
    unsigned w = (unsigned)cnt[t * 4] | ((unsigned)cnt[t * 4 + 1] << 8) |
                 ((unsigned)cnt[t * 4 + 2] << 16) | ((unsigned)cnt[t * 4 + 3] << 24);
    cpack[(n0 >> 2) + t] = w;
  }
}

// ---------------- fused 2-layer MLP, MFMA bf16, LDS-staged ----------------

__launch_bounds__(256)
__global__ void mlp_kernel(const float* __restrict__ x,
                           const ushort_t* __restrict__ W1s, const float* __restrict__ b1,
                           const ushort_t* __restrict__ W2s, const float* __restrict__ b2,
                           ushort_t* __restrict__ mh, unsigned char* __restrict__ h8) {
  __shared__ ushort_t S[64 * 264];  // 33792 B union
  int t = threadIdx.x;
  int wv = t >> 6, lane = t & 63;
  int quad = lane >> 4, l15 = lane & 15;
  int nb = blockIdx.x * 64;

  #pragma unroll
  for (int it = 0; it < 8; ++it) {
    int f = it * 256 + t;
    int row = f >> 5, off4 = f & 31;
    int grow = min(nb + row, NN - 1);
    float4 v = *(const float4*)&x[(size_t)grow * 128 + off4 * 4];
    union { uint2 d; ushort_t u[4]; } pk;
    pk.u[0] = f2bf(v.x); pk.u[1] = f2bf(v.y); pk.u[2] = f2bf(v.z); pk.u[3] = f2bf(v.w);
    *(uint2*)&S[row * 136 + off4 * 4] = pk.d;
  }
  __syncthreads();

  floatx4 acc1[4][4];
  #pragma unroll
  for (int rt = 0; rt < 4; ++rt)
    #pragma unroll
    for (int c = 0; c < 4; ++c) acc1[rt][c] = (floatx4)0.f;

  #pragma unroll
  for (int s = 0; s < 4; ++s) {
    short8 av[4];
    #pragma unroll
    for (int rt = 0; rt < 4; ++rt)
      av[rt] = *(const short8*)&S[(rt * 16 + l15) * 136 + s * 32 + quad * 8];
    #pragma unroll
    for (int c = 0; c < 4; ++c) {
      short8 bv = *(const short8*)&W1s[((s * 16 + wv * 4 + c) * 64 + lane) * 8];
      #pragma unroll
      for (int rt = 0; rt < 4; ++rt)
        acc1[rt][c] = __builtin_amdgcn_mfma_f32_16x16x32_bf16(av[rt], bv, acc1[rt][c], 0, 0, 0);
    }
  }
  __syncthreads();

  #pragma unroll
  for (int c = 0; c < 4; ++c) {
    int col = (wv * 4 + c) * 16 + l15;
    float bb = b1[col];
    #pragma unroll
    for (int rt = 0; rt < 4; ++rt)
      #pragma unroll
      for (int reg = 0; reg < 4; ++reg)
        S[(rt * 16 + quad * 4 + reg) * 264 + col] = f2bf(fmaxf(acc1[rt][c][reg] + bb, 0.f));
  }
  __syncthreads();

  floatx4 acc2[4];
  #pragma unroll
  for (int c = 0; c < 4; ++c) acc2[c] = (floatx4)0.f;
  #pragma unroll
  for (int s = 0; s < 8; ++s) {
    short8 av = *(const short8*)&S[(wv * 16 + l15) * 264 + s * 32 + quad * 8];
    #pragma unroll
    for (int c = 0; c < 4; ++c) {
      short8 bv = *(const short8*)&W2s[((s * 4 + c) * 64 + lane) * 8];
      acc2[c] = __builtin_amdgcn_mfma_f32_16x16x32_bf16(av, bv, acc2[c], 0, 0, 0);
    }
  }
  __syncthreads();

  #pragma unroll
  for (int c = 0; c < 4; ++c) {
    int col = c * 16 + l15;
    float bb = b2[c * 16 + l15];
    #pragma unroll
    for (int reg = 0; reg < 4; ++reg)
      S[(wv * 16 + quad * 4 + reg) * 72 + col] = f2bf(acc2[c][reg] + bb);
  }
  __syncthreads();

  #pragma unroll
  for (int it = 0; it < 2; ++it) {
    int idx = it * 256 + t;
    int row = idx >> 3, ch = idx & 7;
    int node = nb + row;
    if (node < NN) {
      short8 v = *(const short8*)&S[row * 72 + ch * 8];
      *(short8*)&mh[(size_t)node * 64 + ch * 8] = v;
      *(uint2*)&h8[(size_t)node * 64 + ch * 8] = bf8_to_fp8x8(v);
    }
  }
}

// ---------------- persistent cooperative 3-round agg+GRU + fused pool ----------------
// 64 nodes/block as 2x32-node sub-tiles; h lives in registers across rounds
// (no mh round-trip); h8 double-buffered per round; grid.sync() between rounds.
// Round 3 skips the h8 write (never gathered). Pool fused via LDS reduce +
// 129 global atomics per block.

__launch_bounds__(256, 8)
__global__ void agru3_kernel(const ushort_t* __restrict__ mh0,
                             unsigned char* __restrict__ h8a,
                             unsigned char* __restrict__ h8b,
                             const unsigned* __restrict__ cpack,
                             const int* __restrict__ csr, const float* __restrict__ wtab,
                             const ushort_t* __restrict__ Wcs,
                             const float* __restrict__ b_ih, const float* __restrict__ b_hh,
                             const unsigned char* __restrict__ flagb,
                             float* __restrict__ pooled) {
  __shared__ ushort_t As[32 * 136];   // 8704 B
  __shared__ ushort_t Os[32 * 72];    // 4608 B
  __shared__ float wt[16];
  __shared__ float red[129];          // pool: 64 base | 64 flag | cnt
  int t = threadIdx.x;
  int nb = blockIdx.x * 64;
  if (t < 16) wt[t] = (t < 8) ? wtab[t] : 0.f;
  for (int i = t; i < 129; i += 256) red[i] = 0.f;

  int g8 = t >> 3, lane8 = t & 7;
  int wv = t >> 6, lane = t & 63;
  int quad = lane >> 4, l15 = lane & 15;

  // initial h (from MLP) into registers; epilogue biases hoisted
  short8 hreg0, hreg1;
  {
    int n0 = min(nb + g8, NN - 1);
    int n1 = min(nb + 32 + g8, NN - 1);
    hreg0 = *(const short8*)&mh0[(size_t)n0 * 64 + lane8 * 8];
    hreg1 = *(const short8*)&mh0[(size_t)n1 * 64 + lane8 * 8];
  }
  int j = wv * 16 + l15;
  float bir = b_ih[j] + b_hh[j];
  float biz = b_ih[64 + j] + b_hh[64 + j];
  float bin_ = b_ih[128 + j];
  float bhn = b_hh[128 + j];

  cg::grid_group grid = cg::this_grid();
  __syncthreads();  // wt/red visible

  unsigned char* h8cur = h8a;
  unsigned char* h8nxt = h8b;

  #pragma unroll 1
  for (int r = 0; r < 3; ++r) {
    #pragma unroll
    for (int tl = 0; tl < 2; ++tl) {
      short8 hin = tl ? hreg1 : hreg0;
      int node = nb + tl * 32 + g8;
      bool valid = node < NN;
      int deg = 0;
      if (valid) deg = (cpack[node >> 2] >> ((node & 3) * 8)) & 255;
      int sbase = node * CAP;
      float f0 = 0.f, f1 = 0.f, f2 = 0.f, f3 = 0.f;
      float f4 = 0.f, f5 = 0.f, f6 = 0.f, f7 = 0.f;
      for (int p = 0; p < deg; p += 8) {
        int k[8];
        uint2 v[8];
        #pragma unroll
        for (int i = 0; i < 8; ++i) {
          int q = p + i;
          k[i] = (q < deg) ? __builtin_nontemporal_load(&csr[sbase + q]) : (8 << 17);
        }
        #pragma unroll
        for (int i = 0; i < 8; ++i)
          v[i] = *(const uint2*)&h8cur[(size_t)(k[i] & 0x1FFFF) * 64 + lane8 * 8];
        #pragma unroll
        for (int i = 0; i < 8; ++i) {
          float w = wt[k[i] >> 17];
          floatx2 xlo = __builtin_amdgcn_cvt_pk_f32_fp8((int)v[i].x, false);
          floatx2 xhi = __builtin_amdgcn_cvt_pk_f32_fp8((int)v[i].x, true);
          floatx2 ylo = __builtin_amdgcn_cvt_pk_f32_fp8((int)v[i].y, false);
          floatx2 yhi = __builtin_amdgcn_cvt_pk_f32_fp8((int)v[i].y, true);
          f0 += w * xlo[0]; f1 += w * xlo[1]; f2 += w * xhi[0]; f3 += w * xhi[1];
          f4 += w * ylo[0]; f5 += w * ylo[1]; f6 += w * yhi[0]; f7 += w * yhi[1];
        }
      }
      __syncthreads();  // prior sub-tile's As/Os reads complete
      {
        float invd = 1.f / fmaxf((float)deg, 1.f);
        short8 pk;
        pk[0] = (short)f2bf(f0 * invd); pk[1] = (short)f2bf(f1 * invd);
        pk[2] = (short)f2bf(f2 * invd); pk[3] = (short)f2bf(f3 * invd);
        pk[4] = (short)f2bf(f4 * invd); pk[5] = (short)f2bf(f5 * invd);
        pk[6] = (short)f2bf(f6 * invd); pk[7] = (short)f2bf(f7 * invd);
        *(short8*)&As[g8 * 136 + lane8 * 8] = pk;
        *(short8*)&As[g8 * 136 + 64 + lane8 * 8] = hin;
      }
      __syncthreads();

      floatx4 acc[2][4];
      #pragma unroll
      for (int rt = 0; rt < 2; ++rt)
        #pragma unroll
        for (int g = 0; g < 4; ++g) acc[rt][g] = (floatx4)0.f;

      #pragma unroll
      for (int s4 = 0; s4 < 4; ++s4) {
        short8 av[2];
        #pragma unroll
        for (int rt = 0; rt < 2; ++rt)
          av[rt] = *(const short8*)&As[(rt * 16 + l15) * 136 + s4 * 32 + quad * 8];
        #pragma unroll
        for (int g = 0; g < 4; ++g) {
          short8 bv = *(const short8*)&Wcs[((s4 * 16 + g * 4 + wv) * 64 + lane) * 8];
          #pragma unroll
          for (int rt = 0; rt < 2; ++rt)
            acc[rt][g] = __builtin_amdgcn_mfma_f32_16x16x32_bf16(av[rt], bv, acc[rt][g], 0, 0, 0);
        }
      }

      #pragma unroll
      for (int rt = 0; rt < 2; ++rt) {
        #pragma unroll
        for (int reg = 0; reg < 4; ++reg) {
          int lrow = rt * 16 + quad * 4 + reg;
          float rr = sigmoidf_(acc[rt][0][reg] + bir);
          float z = sigmoidf_(acc[rt][1][reg] + biz);
          float n = tanhf_fast(acc[rt][2][reg] + bin_ + rr * (acc[rt][3][reg] + bhn));
          float hp = bf2f(As[lrow * 136 + 64 + j]);
          Os[lrow * 72 + j] = f2bf((1.f - z) * n + z * hp);
        }
      }
      __syncthreads();

      {
        short8 vo = *(const short8*)&Os[g8 * 72 + lane8 * 8];
        if (tl) hreg1 = vo; else hreg0 = vo;
        if (valid && r < 2)
          *(uint2*)&h8nxt[(size_t)node * 64 + lane8 * 8] = bf8_to_fp8x8(vo);
      }
    }
    if (r < 2) {
      grid.sync();
      unsigned char* tmp = h8cur; h8cur = h8nxt; h8nxt = tmp;
    }
  }

  // fused pool: LDS reduce then 129 global atomics per block
  __syncthreads();
  #pragma unroll
  for (int tl = 0; tl < 2; ++tl) {
    short8 hv = tl ? hreg1 : hreg0;
    int node = nb + tl * 32 + g8;
    bool valid = node < NN;
    int fb = valid ? (int)flagb[node] : 0;
    if (valid) {
      #pragma unroll
      for (int c = 0; c < 8; ++c) {
        float val = bf2f((ushort_t)hv[c]);
        atomicAdd(&red[lane8 * 8 + c], val);
        if (fb) atomicAdd(&red[64 + lane8 * 8 + c], val);
      }
      if (fb && lane8 == 0) atomicAdd(&red[128], 1.f);
    }
  }
  __syncthreads();
  if (t < 129) atomicAdd(&pooled[t], red[t]);
}

// ---------------- head ----------------

__global__ void final_kernel(const float* __restrict__ pooled,
                             const float* __restrict__ fc1_w, const float* __restrict__ fc1_b,
                             const float* __restrict__ fc2_w, const float* __restrict__ fc2_b,
                             const float* __restrict__ w_imp, float* __restrict__ out) {
  __shared__ float p[64];
  __shared__ float hid[256];
  __shared__ float o[2];
  int t = threadIdx.x;
  float wpos = softplusf_(w_imp[0]);
  if (t < 64) {
    float num = pooled[t] + wpos * pooled[64 + t];
    float den = (float)NN + wpos * pooled[128];
    p[t] = num / den;
  }
  __syncthreads();
  {
    float a = 0.f;
    for (int k = 0; k < 64; ++k) a += p[k] * fc1_w[t * 64 + k];
    hid[t] = fmaxf(a + fc1_b[t], 0.f);
  }
  __syncthreads();
  if (t < 2) {
    float a = 0.f;
    for (int k = 0; k < 256; ++k) a += hid[k] * fc2_w[t * 256 + k];
    o[t] = a + fc2_b[t];
  }
  __syncthreads();
  if (t == 0) {
    float mx = fmaxf(o[0], o[1]);
    float lse = mx + logf(__expf(o[0] - mx) + __expf(o[1] - mx));
    out[0] = o[0] - lse;
    out[1] = o[1] - lse;
  }
}

// ---------------- launch ----------------

extern "C" void kernel_launch(void* const* d_in, const int* in_sizes, int n_in,
                              void* d_out, int out_size, void* d_ws, size_t ws_size,
                              hipStream_t stream) {
  const float* x        = (const float*)d_in[0];
  const int*   ei       = (const int*)d_in[1];
  const int*   etype    = (const int*)d_in[2];
  const int*   diff_idx = (const int*)d_in[3];
  const float* lin1_w   = (const float*)d_in[4];
  const float* lin1_b   = (const float*)d_in[5];
  const float* lin2_w   = (const float*)d_in[6];
  const float* lin2_b   = (const float*)d_in[7];
  const float* gru_w_ih = (const float*)d_in[8];
  const float* gru_w_hh = (const float*)d_in[9];
  const float* gru_b_ih = (const float*)d_in[10];
  const float* gru_b_hh = (const float*)d_in[11];
  const float* etw      = (const float*)d_in[12];
  const float* fc1_w    = (const float*)d_in[13];
  const float* fc1_b    = (const float*)d_in[14];
  const float* fc2_w    = (const float*)d_in[15];
  const float* fc2_b    = (const float*)d_in[16];
  const float* w_imp    = (const float*)d_in[17];
  float* out = (float*)d_out;

  char* ws = (char*)d_ws;
  size_t off = 0;
  auto alloc = [&](size_t bytes) -> void* {
    void* p = ws + off;
    off += (bytes + 255) & ~(size_t)255;
    return p;
  };
  ushort_t* mh0   = (ushort_t*)alloc((size_t)NN * 64 * 2);
  unsigned char* h8a = (unsigned char*)alloc((size_t)NN * 64);
  unsigned char* h8b = (unsigned char*)alloc((size_t)NN * 64);
  int*   csr      = (int*)  alloc((size_t)NN * CAP * 4);
  ull_t* staging  = (ull_t*)alloc((size_t)NQ * NSH * SQS * 8);   // 13.1 MB
  ushort_t* W1s   = (ushort_t*)alloc(128 * 256 * 2);
  ushort_t* W2s   = (ushort_t*)alloc(256 * 64 * 2);
  ushort_t* Wcs   = (ushort_t*)alloc(128 * 256 * 2);
  float* wtab     = (float*)alloc(8 * 4);
  // zeroed block: gtail (1600 line-padded counters, 100KB) | cpack (NN bytes) |
  //               flag bytes (NN) | pooled (129 floats)
  const size_t gtb = (size_t)NQ * NSH * 16 * 4;   // 102400
  char* zbase     = (char*)alloc(gtb + (size_t)NN + NN + 129 * 4);
  unsigned* gtail = (unsigned*)zbase;
  unsigned* cpack = (unsigned*)(zbase + gtb);
  unsigned char* flagb = (unsigned char*)(zbase + gtb + NN);
  float* pooled   = (float*)(zbase + gtb + NN + NN);
  const size_t zbytes = gtb + (size_t)NN + NN + 129 * 4;

  const int ngemm = (NN + 63) / 64;            // 1563
  const int nbin  = (NE + SLICE - 1) / SLICE;  // 586

  hipMemsetAsync(zbase, 0, zbytes, stream);
  prep_w_kernel<<<320, 256, 0, stream>>>(lin1_w, lin2_w, gru_w_ih, gru_w_hh, etw, diff_idx,
                                         W1s, W2s, Wcs, wtab, flagb);
  bin_kernel<<<nbin, 256, 0, stream>>>(ei, ei + NE, etype, gtail, staging);
  scatter_kernel<<<NQ, 512, 0, stream>>>(staging, gtail, cpack, csr);
  mlp_kernel<<<ngemm, 256, 0, stream>>>(x, W1s, lin1_b, W2s, lin2_b, mh0, h8a);

  {
    const ushort_t* a_mh0 = mh0;
    unsigned char* a_h8a = h8a;
    unsigned char* a_h8b = h8b;
    const unsigned* a_cpack = cpack;
    const int* a_csr = csr;
    const float* a_wtab = wtab;
    const ushort_t* a_Wcs = Wcs;
    const float* a_bih = gru_b_ih;
    const float* a_bhh = gru_b_hh;
    const unsigned char* a_flag = flagb;
    float* a_pooled = pooled;
    void* args[] = {(void*)&a_mh0, (void*)&a_h8a, (void*)&a_h8b, (void*)&a_cpack,
                    (void*)&a_csr, (void*)&a_wtab, (void*)&a_Wcs, (void*)&a_bih,
                    (void*)&a_bhh, (void*)&a_flag, (void*)&a_pooled};
    hipLaunchCooperativeKernel((const void*)agru3_kernel, dim3(PB), dim3(256),
                               args, 0, stream);
  }

  final_kernel<<<1, 256, 0, stream>>>(pooled, fc1_w, fc1_b, fc2_w, fc2_b, w_imp, out);
}

// Round 8
// 322.606 us; speedup vs baseline: 2.9333x; 2.9333x over previous
//
#include <hip/hip_runtime.h>
#include <math.h>

#define NN 100000
#define NE 1200000
#define NDIFF 1000
#define CAP 48        // per-node edge bucket capacity; Poisson(12) tail at 48 ~1e-15
#define SLICE 2048    // edges per bin block
#define NQ 200        // node-range queues (SUBN nodes each); NQ*SUBN == NN
#define SUBN 500      // nodes per queue / per scatter block
#define QCAPB 32      // per-block per-queue LDS bin capacity (mean 10.2, +8sd)
#define NSH 8         // queue shards (blockIdx&7 ~ XCD) for write-combined flush
#define SQS 1024      // records per (queue,shard): mean 750, sd 27, +10sd
#define NSPLAY 32     // pooled-accumulator splay copies (contention /32)
#define PSTRIDE 132   // floats per splay copy (129 rounded up)

typedef short short8 __attribute__((ext_vector_type(8)));
typedef float floatx4 __attribute__((ext_vector_type(4)));
typedef float floatx2 __attribute__((ext_vector_type(2)));
typedef unsigned short ushort_t;
typedef unsigned long long ull_t;

__device__ __forceinline__ float softplusf_(float x) {
  return fmaxf(x, 0.f) + logf(1.f + __expf(-fabsf(x)));
}
__device__ __forceinline__ float sigmoidf_(float x) {
  return 1.f / (1.f + __expf(-x));
}
__device__ __forceinline__ float tanhf_fast(float x) {
  float ax = fabsf(x);
  float e = __expf(-2.f * ax);
  float t = (1.f - e) / (1.f + e);
  return x < 0.f ? -t : t;
}
__device__ __forceinline__ ushort_t f2bf(float f) {
  unsigned u = __float_as_uint(f);
  unsigned r = (u + 0x7FFFu + ((u >> 16) & 1u)) >> 16;
  return (ushort_t)r;
}
__device__ __forceinline__ float bf2f(ushort_t s) {
  return __uint_as_float(((unsigned)s) << 16);
}
// pack 8 bf16 (short8) -> 8 fp8 e4m3 bytes (uint2)
__device__ __forceinline__ uint2 bf8_to_fp8x8(short8 v) {
  float f[8];
  #pragma unroll
  for (int i = 0; i < 8; ++i) f[i] = bf2f((ushort_t)v[i]);
  int a = 0, b = 0;
  a = __builtin_amdgcn_cvt_pk_fp8_f32(f[0], f[1], a, false);
  a = __builtin_amdgcn_cvt_pk_fp8_f32(f[2], f[3], a, true);
  b = __builtin_amdgcn_cvt_pk_fp8_f32(f[4], f[5], b, false);
  b = __builtin_amdgcn_cvt_pk_fp8_f32(f[6], f[7], b, true);
  uint2 r; r.x = (unsigned)a; r.y = (unsigned)b;
  return r;
}

// ---------------- setup: fragment-major weights + wtab + diff scatter ----------------

__global__ void prep_w_kernel(const float* __restrict__ lin1_w, const float* __restrict__ lin2_w,
                              const float* __restrict__ w_ih, const float* __restrict__ w_hh,
                              const float* __restrict__ etw, const int* __restrict__ diff,
                              ushort_t* __restrict__ W1s, ushort_t* __restrict__ W2s,
                              ushort_t* __restrict__ Wcs, float* __restrict__ wtab,
                              unsigned char* __restrict__ flagb) {
  int i = blockIdx.x * 256 + threadIdx.x;  // 0..81919
  if (i < 8) wtab[i] = softplusf_(etw[i]);
  if (i < NDIFF) flagb[diff[i]] = 1;
  if (i < 32768) {
    int fi = i >> 9, lane = (i >> 3) & 63, j = i & 7;
    int s = fi >> 4, ct = fi & 15;
    int quad = lane >> 4, l15 = lane & 15;
    int col = ct * 16 + l15, k = s * 32 + quad * 8 + j;
    W1s[i] = f2bf(lin1_w[col * 128 + k]);
  } else if (i < 49152) {
    int i2 = i - 32768;
    int fi = i2 >> 9, lane = (i2 >> 3) & 63, j = i2 & 7;
    int s = fi >> 2, ct = fi & 3;
    int quad = lane >> 4, l15 = lane & 15;
    int col = ct * 16 + l15, k = s * 32 + quad * 8 + j;
    W2s[i2] = f2bf(lin2_w[col * 256 + k]);
  } else {
    int i3 = i - 49152;
    int fi = i3 >> 9, lane = (i3 >> 3) & 63, j = i3 & 7;
    int s = fi >> 4, ct = fi & 15;
    int quad = lane >> 4, l15 = lane & 15;
    int jj = ct * 16 + l15, k = s * 32 + quad * 8 + j;
    float v;
    if (jj < 128)      v = (k < 64) ? w_ih[jj * 64 + k] : w_hh[jj * 64 + (k - 64)];
    else if (jj < 192) v = (k < 64) ? w_ih[jj * 64 + k] : 0.f;
    else               v = (k < 64) ? 0.f : w_hh[(jj - 64) * 64 + (k - 64)];
    Wcs[i3] = f2bf(v);
  }
}

// ---------------- two-phase CSR build, amplification-free ----------------

__launch_bounds__(256)
__global__ void bin_kernel(const int* __restrict__ src, const int* __restrict__ dst,
                           const int* __restrict__ etype,
                           unsigned* __restrict__ gtail, ull_t* __restrict__ staging) {
  __shared__ uint2 bin[NQ][QCAPB];   // 51200 B
  __shared__ unsigned lcur[NQ];      // 800 B
  int t = threadIdx.x;
  int shard = blockIdx.x & 7;
  for (int i = t; i < NQ; i += 256) lcur[i] = 0;
  __syncthreads();
  int base = blockIdx.x * SLICE;

  uint2 rec[8];
  int qq[8];
  unsigned idx[8];
  #pragma unroll
  for (int it = 0; it < 8; ++it) {
    int e = base + it * 256 + t;
    qq[it] = -1;
    if (e < NE) {
      int d = __builtin_nontemporal_load(&dst[e]);
      int s = __builtin_nontemporal_load(&src[e]);
      int tv = __builtin_nontemporal_load(&etype[e]);
      rec[it].x = (unsigned)(s | (tv << 17));
      rec[it].y = (unsigned)d;
      int q = d / SUBN;
      qq[it] = q;
      unsigned i = atomicAdd(&lcur[q], 1u);
      idx[it] = i;
      if (i < QCAPB) bin[q][i] = rec[it];
    }
  }
  __syncthreads();
  // flush: one thread per queue -> one tail atomic + contiguous copy
  if (t < NQ) {
    unsigned c = min(lcur[t], (unsigned)QCAPB);
    if (c) {
      unsigned gb = atomicAdd(&gtail[(t * NSH + shard) * 16], c);
      ull_t* qst = staging + (size_t)(t * NSH + shard) * SQS + gb;
      const uint2* b = bin[t];
      for (unsigned i = 0; i < c; ++i)
        qst[i] = ((ull_t)b[i].y << 32) | (ull_t)b[i].x;
    }
  }
  // overflow stragglers (probability ~1e-3 per grid; correctness fallback)
  #pragma unroll
  for (int it = 0; it < 8; ++it) {
    if (qq[it] >= 0 && idx[it] >= QCAPB) {
      unsigned gb = atomicAdd(&gtail[(qq[it] * NSH + shard) * 16], 1u);
      staging[(size_t)(qq[it] * NSH + shard) * SQS + gb] =
          ((ull_t)rec[it].y << 32) | (ull_t)rec[it].x;
    }
  }
}

__launch_bounds__(512)
__global__ void scatter_kernel(const ull_t* __restrict__ staging,
                               const unsigned* __restrict__ gtail,
                               unsigned* __restrict__ cpack, int* __restrict__ csr) {
  __shared__ int cnt[SUBN];
  int t = threadIdx.x;
  int q = blockIdx.x;
  int n0 = q * SUBN;
  for (int i = t; i < SUBN; i += 512) cnt[i] = 0;
  __syncthreads();

  #pragma unroll 1
  for (int sh = 0; sh < NSH; ++sh) {
    unsigned n = gtail[(q * NSH + sh) * 16];
    const ull_t* st = staging + (size_t)(q * NSH + sh) * SQS;
    for (unsigned i = t; i < n; i += 512) {
      ull_t r = st[i];
      int d = (int)(r >> 32);
      int rank = atomicAdd(&cnt[d - n0], 1);
      csr[d * CAP + rank] = (int)(unsigned)r;
    }
  }
  __syncthreads();

  if (t < SUBN / 4) {
    unsigned w = (unsigned)cnt[t * 4] | ((unsigned)cnt[t * 4 + 1] << 8) |
                 ((unsigned)cnt[t * 4 + 2] << 16) | ((unsigned)cnt[t * 4 + 3] << 24);
    cpack[(n0 >> 2) + t] = w;
  }
}

// ---------------- fused 2-layer MLP, MFMA bf16, LDS-staged ----------------

__launch_bounds__(256)
__global__ void mlp_kernel(const float* __restrict__ x,
                           const ushort_t* __restrict__ W1s, const float* __restrict__ b1,
                           const ushort_t* __restrict__ W2s, const float* __restrict__ b2,
                           ushort_t* __restrict__ mh, unsigned char* __restrict__ h8) {
  __shared__ ushort_t S[64 * 264];  // 33792 B union
  int t = threadIdx.x;
  int wv = t >> 6, lane = t & 63;
  int quad = lane >> 4, l15 = lane & 15;
  int nb = blockIdx.x * 64;

  #pragma unroll
  for (int it = 0; it < 8; ++it) {
    int f = it * 256 + t;
    int row = f >> 5, off4 = f & 31;
    int grow = min(nb + row, NN - 1);
    float4 v = *(const float4*)&x[(size_t)grow * 128 + off4 * 4];
    union { uint2 d; ushort_t u[4]; } pk;
    pk.u[0] = f2bf(v.x); pk.u[1] = f2bf(v.y); pk.u[2] = f2bf(v.z); pk.u[3] = f2bf(v.w);
    *(uint2*)&S[row * 136 + off4 * 4] = pk.d;
  }
  __syncthreads();

  floatx4 acc1[4][4];
  #pragma unroll
  for (int rt = 0; rt < 4; ++rt)
    #pragma unroll
    for (int c = 0; c < 4; ++c) acc1[rt][c] = (floatx4)0.f;

  #pragma unroll
  for (int s = 0; s < 4; ++s) {
    short8 av[4];
    #pragma unroll
    for (int rt = 0; rt < 4; ++rt)
      av[rt] = *(const short8*)&S[(rt * 16 + l15) * 136 + s * 32 + quad * 8];
    #pragma unroll
    for (int c = 0; c < 4; ++c) {
      short8 bv = *(const short8*)&W1s[((s * 16 + wv * 4 + c) * 64 + lane) * 8];
      #pragma unroll
      for (int rt = 0; rt < 4; ++rt)
        acc1[rt][c] = __builtin_amdgcn_mfma_f32_16x16x32_bf16(av[rt], bv, acc1[rt][c], 0, 0, 0);
    }
  }
  __syncthreads();

  #pragma unroll
  for (int c = 0; c < 4; ++c) {
    int col = (wv * 4 + c) * 16 + l15;
    float bb = b1[col];
    #pragma unroll
    for (int rt = 0; rt < 4; ++rt)
      #pragma unroll
      for (int reg = 0; reg < 4; ++reg)
        S[(rt * 16 + quad * 4 + reg) * 264 + col] = f2bf(fmaxf(acc1[rt][c][reg] + bb, 0.f));
  }
  __syncthreads();

  floatx4 acc2[4];
  #pragma unroll
  for (int c = 0; c < 4; ++c) acc2[c] = (floatx4)0.f;
  #pragma unroll
  for (int s = 0; s < 8; ++s) {
    short8 av = *(const short8*)&S[(wv * 16 + l15) * 264 + s * 32 + quad * 8];
    #pragma unroll
    for (int c = 0; c < 4; ++c) {
      short8 bv = *(const short8*)&W2s[((s * 4 + c) * 64 + lane) * 8];
      acc2[c] = __builtin_amdgcn_mfma_f32_16x16x32_bf16(av, bv, acc2[c], 0, 0, 0);
    }
  }
  __syncthreads();

  #pragma unroll
  for (int c = 0; c < 4; ++c) {
    int col = c * 16 + l15;
    float bb = b2[c * 16 + l15];
    #pragma unroll
    for (int reg = 0; reg < 4; ++reg)
      S[(wv * 16 + quad * 4 + reg) * 72 + col] = f2bf(acc2[c][reg] + bb);
  }
  __syncthreads();

  #pragma unroll
  for (int it = 0; it < 2; ++it) {
    int idx = it * 256 + t;
    int row = idx >> 3, ch = idx & 7;
    int node = nb + row;
    if (node < NN) {
      short8 v = *(const short8*)&S[row * 72 + ch * 8];
      *(short8*)&mh[(size_t)node * 64 + ch * 8] = v;
      *(uint2*)&h8[(size_t)node * 64 + ch * 8] = bf8_to_fp8x8(v);
    }
  }
}

// ---------------- fused aggregation + GRU, 256 threads / 32 nodes ----------------
// LAST=true: skip mh/h8 output, fuse importance-weighted pooling (in-register
// partial sums -> LDS -> 32-way-splayed global accumulator).

template <bool LAST>
__launch_bounds__(256, 8)
__global__ void agru_kernel(const ushort_t* __restrict__ mhin,
                            const unsigned char* __restrict__ h8in,
                            const unsigned* __restrict__ cpack,
                            const int* __restrict__ csr, const float* __restrict__ wtab,
                            const ushort_t* __restrict__ Wcs,
                            const float* __restrict__ b_ih, const float* __restrict__ b_hh,
                            ushort_t* __restrict__ mhout, unsigned char* __restrict__ h8out,
                            const unsigned char* __restrict__ flagb,
                            float* __restrict__ pooled) {
  __shared__ ushort_t As[32 * 136];   // 8704 B
  __shared__ ushort_t Os[32 * 72];    // 4608 B
  __shared__ float wt[16];
  __shared__ float red[132];
  int t = threadIdx.x;
  int nb = blockIdx.x * 32;
  if (t < 16) wt[t] = (t < 8) ? wtab[t] : 0.f;
  if (LAST) { for (int i = t; i < 132; i += 256) red[i] = 0.f; }
  __syncthreads();   // wt/red visible; no memory ops pending

  int g8 = t >> 3, lane8 = t & 7;
  int node = nb + g8;

  // issue h load (consumed only after agg -> latency hidden)
  short8 hreg = *(const short8*)&mhin[(size_t)node * 64 + lane8 * 8];

  // aggregation: one row per 8-lane group, all batches padded to 8
  int deg = (cpack[node >> 2] >> ((node & 3) * 8)) & 255;
  int s = node * CAP;
  float f0 = 0.f, f1 = 0.f, f2 = 0.f, f3 = 0.f;
  float f4 = 0.f, f5 = 0.f, f6 = 0.f, f7 = 0.f;
  for (int p = 0; p < deg; p += 8) {
    int k[8];
    uint2 v[8];
    #pragma unroll
    for (int i = 0; i < 8; ++i) {
      int q = p + i;
      k[i] = (q < deg) ? __builtin_nontemporal_load(&csr[s + q]) : (8 << 17);
    }
    #pragma unroll
    for (int i = 0; i < 8; ++i)
      v[i] = *(const uint2*)&h8in[(size_t)(k[i] & 0x1FFFF) * 64 + lane8 * 8];
    #pragma unroll
    for (int i = 0; i < 8; ++i) {
      float w = wt[k[i] >> 17];
      floatx2 xlo = __builtin_amdgcn_cvt_pk_f32_fp8((int)v[i].x, false);
      floatx2 xhi = __builtin_amdgcn_cvt_pk_f32_fp8((int)v[i].x, true);
      floatx2 ylo = __builtin_amdgcn_cvt_pk_f32_fp8((int)v[i].y, false);
      floatx2 yhi = __builtin_amdgcn_cvt_pk_f32_fp8((int)v[i].y, true);
      f0 += w * xlo[0]; f1 += w * xlo[1]; f2 += w * xhi[0]; f3 += w * xhi[1];
      f4 += w * ylo[0]; f5 += w * ylo[1]; f6 += w * yhi[0]; f7 += w * yhi[1];
    }
  }
  {
    float invd = 1.f / fmaxf((float)deg, 1.f);
    short8 pk;
    pk[0] = (short)f2bf(f0 * invd); pk[1] = (short)f2bf(f1 * invd);
    pk[2] = (short)f2bf(f2 * invd); pk[3] = (short)f2bf(f3 * invd);
    pk[4] = (short)f2bf(f4 * invd); pk[5] = (short)f2bf(f5 * invd);
    pk[6] = (short)f2bf(f6 * invd); pk[7] = (short)f2bf(f7 * invd);
    *(short8*)&As[g8 * 136 + lane8 * 8] = pk;
    *(short8*)&As[g8 * 136 + 64 + lane8 * 8] = hreg;
  }
  __syncthreads();

  // GEMM: [32 nodes x 128] @ Wcs[128 x 256]; wave wv = col-quarter
  int wv = t >> 6, lane = t & 63;
  int quad = lane >> 4, l15 = lane & 15;

  floatx4 acc[2][4];
  #pragma unroll
  for (int rt = 0; rt < 2; ++rt)
    #pragma unroll
    for (int g = 0; g < 4; ++g) acc[rt][g] = (floatx4)0.f;

  #pragma unroll
  for (int s4 = 0; s4 < 4; ++s4) {
    short8 av[2];
    #pragma unroll
    for (int rt = 0; rt < 2; ++rt)
      av[rt] = *(const short8*)&As[(rt * 16 + l15) * 136 + s4 * 32 + quad * 8];
    #pragma unroll
    for (int g = 0; g < 4; ++g) {
      short8 bv = *(const short8*)&Wcs[((s4 * 16 + g * 4 + wv) * 64 + lane) * 8];
      #pragma unroll
      for (int rt = 0; rt < 2; ++rt)
        acc[rt][g] = __builtin_amdgcn_mfma_f32_16x16x32_bf16(av[rt], bv, acc[rt][g], 0, 0, 0);
    }
  }

  int j = wv * 16 + l15;
  float bir = b_ih[j] + b_hh[j];
  float biz = b_ih[64 + j] + b_hh[64 + j];
  float bin_ = b_ih[128 + j];
  float bhn = b_hh[128 + j];

  if (!LAST) {
    #pragma unroll
    for (int rt = 0; rt < 2; ++rt) {
      #pragma unroll
      for (int reg = 0; reg < 4; ++reg) {
        int lrow = rt * 16 + quad * 4 + reg;
        float r = sigmoidf_(acc[rt][0][reg] + bir);
        float z = sigmoidf_(acc[rt][1][reg] + biz);
        float n = tanhf_fast(acc[rt][2][reg] + bin_ + r * (acc[rt][3][reg] + bhn));
        float hp = bf2f(As[lrow * 136 + 64 + j]);
        Os[lrow * 72 + j] = f2bf((1.f - z) * n + z * hp);
      }
    }
    __syncthreads();
    short8 vo = *(const short8*)&Os[g8 * 72 + lane8 * 8];
    *(short8*)&mhout[(size_t)node * 64 + lane8 * 8] = vo;
    *(uint2*)&h8out[(size_t)node * 64 + lane8 * 8] = bf8_to_fp8x8(vo);
  } else {
    // pool partials in registers: channel j, 8 rows per thread
    float psum = 0.f, fsum = 0.f;
    #pragma unroll
    for (int rt = 0; rt < 2; ++rt) {
      #pragma unroll
      for (int reg = 0; reg < 4; ++reg) {
        int lrow = rt * 16 + quad * 4 + reg;
        float r = sigmoidf_(acc[rt][0][reg] + bir);
        float z = sigmoidf_(acc[rt][1][reg] + biz);
        float n = tanhf_fast(acc[rt][2][reg] + bin_ + r * (acc[rt][3][reg] + bhn));
        float hp = bf2f(As[lrow * 136 + 64 + j]);
        float hn = (1.f - z) * n + z * hp;
        psum += hn;
        if (flagb[nb + lrow]) fsum += hn;
      }
    }
    atomicAdd(&red[j], psum);          // 4-way LDS contention (quad)
    atomicAdd(&red[64 + j], fsum);
    if (t < 32) { if (flagb[nb + t]) atomicAdd(&red[128], 1.f); }
    __syncthreads();
    if (t < 129) atomicAdd(&pooled[(blockIdx.x & (NSPLAY - 1)) * PSTRIDE + t], red[t]);
  }
}

// ---------------- head (folds 32 splayed pool copies) ----------------

__global__ void final_kernel(const float* __restrict__ pooled,
                             const float* __restrict__ fc1_w, const float* __restrict__ fc1_b,
                             const float* __restrict__ fc2_w, const float* __restrict__ fc2_b,
                             const float* __restrict__ w_imp, float* __restrict__ out) {
  __shared__ float p[64];
  __shared__ float hid[256];
  __shared__ float o[2];
  __shared__ float cnt_s;
  int t = threadIdx.x;
  float wpos = softplusf_(w_imp[0]);
  float b = 0.f, f = 0.f;
  if (t < 64) {
    #pragma unroll 4
    for (int k = 0; k < NSPLAY; ++k) {
      b += pooled[k * PSTRIDE + t];
      f += pooled[k * PSTRIDE + 64 + t];
    }
  }
  if (t == 64) {
    float c = 0.f;
    for (int k = 0; k < NSPLAY; ++k) c += pooled[k * PSTRIDE + 128];
    cnt_s = c;
  }
  __syncthreads();
  if (t < 64) {
    float den = (float)NN + wpos * cnt_s;
    p[t] = (b + wpos * f) / den;
  }
  __syncthreads();
  {
    float a = 0.f;
    for (int k = 0; k < 64; ++k) a += p[k] * fc1_w[t * 64 + k];
    hid[t] = fmaxf(a + fc1_b[t], 0.f);
  }
  __syncthreads();
  if (t < 2) {
    float a = 0.f;
    for (int k = 0; k < 256; ++k) a += hid[k] * fc2_w[t * 256 + k];
    o[t] = a + fc2_b[t];
  }
  __syncthreads();
  if (t == 0) {
    float mx = fmaxf(o[0], o[1]);
    float lse = mx + logf(__expf(o[0] - mx) + __expf(o[1] - mx));
    out[0] = o[0] - lse;
    out[1] = o[1] - lse;
  }
}

// ---------------- launch ----------------

extern "C" void kernel_launch(void* const* d_in, const int* in_sizes, int n_in,
                              void* d_out, int out_size, void* d_ws, size_t ws_size,
                              hipStream_t stream) {
  const float* x        = (const float*)d_in[0];
  const int*   ei       = (const int*)d_in[1];
  const int*   etype    = (const int*)d_in[2];
  const int*   diff_idx = (const int*)d_in[3];
  const float* lin1_w   = (const float*)d_in[4];
  const float* lin1_b   = (const float*)d_in[5];
  const float* lin2_w   = (const float*)d_in[6];
  const float* lin2_b   = (const float*)d_in[7];
  const float* gru_w_ih = (const float*)d_in[8];
  const float* gru_w_hh = (const float*)d_in[9];
  const float* gru_b_ih = (const float*)d_in[10];
  const float* gru_b_hh = (const float*)d_in[11];
  const float* etw      = (const float*)d_in[12];
  const float* fc1_w    = (const float*)d_in[13];
  const float* fc1_b    = (const float*)d_in[14];
  const float* fc2_w    = (const float*)d_in[15];
  const float* fc2_b    = (const float*)d_in[16];
  const float* w_imp    = (const float*)d_in[17];
  float* out = (float*)d_out;

  char* ws = (char*)d_ws;
  size_t off = 0;
  auto alloc = [&](size_t bytes) -> void* {
    void* p = ws + off;
    off += (bytes + 255) & ~(size_t)255;
    return p;
  };
  ushort_t* mh0   = (ushort_t*)alloc((size_t)NN * 64 * 2);
  ushort_t* mh1   = (ushort_t*)alloc((size_t)NN * 64 * 2);
  unsigned char* h8a = (unsigned char*)alloc((size_t)NN * 64);
  unsigned char* h8b = (unsigned char*)alloc((size_t)NN * 64);
  int*   csr      = (int*)  alloc((size_t)NN * CAP * 4);
  ull_t* staging  = (ull_t*)alloc((size_t)NQ * NSH * SQS * 8);   // 13.1 MB
  ushort_t* W1s   = (ushort_t*)alloc(128 * 256 * 2);
  ushort_t* W2s   = (ushort_t*)alloc(256 * 64 * 2);
  ushort_t* Wcs   = (ushort_t*)alloc(128 * 256 * 2);
  float* wtab     = (float*)alloc(8 * 4);
  // zeroed block: gtail (1600 line-padded counters, 100KB) | cpack (NN bytes) |
  //               flag bytes (NN) | pooled (32 splayed copies x 132 floats)
  const size_t gtb = (size_t)NQ * NSH * 16 * 4;   // 102400
  const size_t plb = (size_t)NSPLAY * PSTRIDE * 4;
  char* zbase     = (char*)alloc(gtb + (size_t)NN + NN + plb);
  unsigned* gtail = (unsigned*)zbase;
  unsigned* cpack = (unsigned*)(zbase + gtb);
  unsigned char* flagb = (unsigned char*)(zbase + gtb + NN);
  float* pooled   = (float*)(zbase + gtb + NN + NN);
  const size_t zbytes = gtb + (size_t)NN + NN + plb;

  const int ngemm = (NN + 63) / 64;            // 1563
  const int nagru = NN / 32;                   // 3125 exactly
  const int nbin  = (NE + SLICE - 1) / SLICE;  // 586

  hipMemsetAsync(zbase, 0, zbytes, stream);
  prep_w_kernel<<<320, 256, 0, stream>>>(lin1_w, lin2_w, gru_w_ih, gru_w_hh, etw, diff_idx,
                                         W1s, W2s, Wcs, wtab, flagb);
  bin_kernel<<<nbin, 256, 0, stream>>>(ei, ei + NE, etype, gtail, staging);
  scatter_kernel<<<NQ, 512, 0, stream>>>(staging, gtail, cpack, csr);
  mlp_kernel<<<ngemm, 256, 0, stream>>>(x, W1s, lin1_b, W2s, lin2_b, mh0, h8a);

  agru_kernel<false><<<nagru, 256, 0, stream>>>(mh0, h8a, cpack, csr, wtab, Wcs,
                                                gru_b_ih, gru_b_hh, mh1, h8b, flagb, pooled);
  agru_kernel<false><<<nagru, 256, 0, stream>>>(mh1, h8b, cpack, csr, wtab, Wcs,
                                                gru_b_ih, gru_b_hh, mh0, h8a, flagb, pooled);
  agru_kernel<true><<<nagru, 256, 0, stream>>>(mh0, h8a, cpack, csr, wtab, Wcs,
                                               gru_b_ih, gru_b_hh, mh1, h8b, flagb, pooled);

  final_kernel<<<1, 256, 0, stream>>>(pooled, fc1_w, fc1_b, fc2_w, fc2_b, w_imp, out);
}

// Round 10
// 293.481 us; speedup vs baseline: 3.2244x; 1.0992x over previous
//
#include <hip/hip_runtime.h>
#include <math.h>

#define NN 100000
#define NE 1200000
#define NDIFF 1000
#define CAP 48        // per-node edge bucket capacity; Poisson(12) tail at 48 ~1e-15
#define SLICE 2048    // edges per bin block
#define NQ 200        // node-range queues (SUBN nodes each); NQ*SUBN == NN
#define SUBN 500      // nodes per queue / per scatter block
#define QCAPB 32      // per-block per-queue LDS bin capacity (mean 10.2, +8sd)
#define NSH 8         // queue shards (bin-block & 7) for write-combined flush
#define SQS 1024      // records per (queue,shard): mean 750, sd 27, +10sd
#define NSPLAY 32     // pooled-accumulator splay copies (contention /32)
#define PSTRIDE 132   // floats per splay copy (129 rounded up)
#define NGEMM 1563    // (NN+63)/64
#define NBIN 586      // (NE+SLICE-1)/SLICE

typedef short short8 __attribute__((ext_vector_type(8)));
typedef float floatx4 __attribute__((ext_vector_type(4)));
typedef float floatx2 __attribute__((ext_vector_type(2)));
typedef int intx4 __attribute__((ext_vector_type(4)));
typedef unsigned short ushort_t;
typedef unsigned long long ull_t;

__device__ __forceinline__ float softplusf_(float x) {
  return fmaxf(x, 0.f) + logf(1.f + __expf(-fabsf(x)));
}
__device__ __forceinline__ float sigmoidf_(float x) {
  return 1.f / (1.f + __expf(-x));
}
__device__ __forceinline__ float tanhf_fast(float x) {
  float ax = fabsf(x);
  float e = __expf(-2.f * ax);
  float t = (1.f - e) / (1.f + e);
  return x < 0.f ? -t : t;
}
__device__ __forceinline__ ushort_t f2bf(float f) {
  unsigned u = __float_as_uint(f);
  unsigned r = (u + 0x7FFFu + ((u >> 16) & 1u)) >> 16;
  return (ushort_t)r;
}
__device__ __forceinline__ float bf2f(ushort_t s) {
  return __uint_as_float(((unsigned)s) << 16);
}
// pack 8 bf16 (short8) -> 8 fp8 e4m3 bytes (uint2)
__device__ __forceinline__ uint2 bf8_to_fp8x8(short8 v) {
  float f[8];
  #pragma unroll
  for (int i = 0; i < 8; ++i) f[i] = bf2f((ushort_t)v[i]);
  int a = 0, b = 0;
  a = __builtin_amdgcn_cvt_pk_fp8_f32(f[0], f[1], a, false);
  a = __builtin_amdgcn_cvt_pk_fp8_f32(f[2], f[3], a, true);
  b = __builtin_amdgcn_cvt_pk_fp8_f32(f[4], f[5], b, false);
  b = __builtin_amdgcn_cvt_pk_fp8_f32(f[6], f[7], b, true);
  uint2 r; r.x = (unsigned)a; r.y = (unsigned)b;
  return r;
}

// ---------------- setup: fragment-major weights + wtab + diff scatter ----------------

__global__ void prep_w_kernel(const float* __restrict__ lin1_w, const float* __restrict__ lin2_w,
                              const float* __restrict__ w_ih, const float* __restrict__ w_hh,
                              const float* __restrict__ etw, const int* __restrict__ diff,
                              ushort_t* __restrict__ W1s, ushort_t* __restrict__ W2s,
                              ushort_t* __restrict__ Wcs, float* __restrict__ wtab,
                              unsigned char* __restrict__ flagb) {
  int i = blockIdx.x * 256 + threadIdx.x;  // 0..81919
  if (i < 8) wtab[i] = softplusf_(etw[i]);
  if (i < NDIFF) flagb[diff[i]] = 1;
  if (i < 32768) {
    int fi = i >> 9, lane = (i >> 3) & 63, j = i & 7;
    int s = fi >> 4, ct = fi & 15;
    int quad = lane >> 4, l15 = lane & 15;
    int col = ct * 16 + l15, k = s * 32 + quad * 8 + j;
    W1s[i] = f2bf(lin1_w[col * 128 + k]);
  } else if (i < 49152) {
    int i2 = i - 32768;
    int fi = i2 >> 9, lane = (i2 >> 3) & 63, j = i2 & 7;
    int s = fi >> 2, ct = fi & 3;
    int quad = lane >> 4, l15 = lane & 15;
    int col = ct * 16 + l15, k = s * 32 + quad * 8 + j;
    W2s[i2] = f2bf(lin2_w[col * 256 + k]);
  } else {
    int i3 = i - 49152;
    int fi = i3 >> 9, lane = (i3 >> 3) & 63, j = i3 & 7;
    int s = fi >> 4, ct = fi & 15;
    int quad = lane >> 4, l15 = lane & 15;
    int jj = ct * 16 + l15, k = s * 32 + quad * 8 + j;
    float v;
    if (jj < 128)      v = (k < 64) ? w_ih[jj * 64 + k] : w_hh[jj * 64 + (k - 64)];
    else if (jj < 192) v = (k < 64) ? w_ih[jj * 64 + k] : 0.f;
    else               v = (k < 64) ? 0.f : w_hh[(jj - 64) * 64 + (k - 64)];
    Wcs[i3] = f2bf(v);
  }
}

// ---------------- fused (MLP union bin) kernel ----------------
// Blocks [0, NGEMM): 2-layer MFMA MLP (compute-bound).
// Blocks [NGEMM, NGEMM+NBIN): edge binning (memory-bound) — hides under MLP.
// 4-byte staging records: (local_d << 20) | (etype << 17) | src  (29 bits).

__launch_bounds__(256)
__global__ void binmlp_kernel(const float* __restrict__ x,
                              const ushort_t* __restrict__ W1s, const float* __restrict__ b1,
                              const ushort_t* __restrict__ W2s, const float* __restrict__ b2,
                              ushort_t* __restrict__ mh, unsigned char* __restrict__ h8,
                              const int* __restrict__ src, const int* __restrict__ dst,
                              const int* __restrict__ etype,
                              unsigned* __restrict__ gtail, unsigned* __restrict__ staging) {
  __shared__ __align__(16) char U[33792];   // union: mlp S (33792B) | bin 25600+800B
  int t = threadIdx.x;

  if (blockIdx.x < NGEMM) {
    // ---------------- MLP ----------------
    ushort_t* S = (ushort_t*)U;
    int wv = t >> 6, lane = t & 63;
    int quad = lane >> 4, l15 = lane & 15;
    int nb = blockIdx.x * 64;

    #pragma unroll
    for (int it = 0; it < 8; ++it) {
      int f = it * 256 + t;
      int row = f >> 5, off4 = f & 31;
      int grow = min(nb + row, NN - 1);
      float4 v = *(const float4*)&x[(size_t)grow * 128 + off4 * 4];
      union { uint2 d; ushort_t u[4]; } pk;
      pk.u[0] = f2bf(v.x); pk.u[1] = f2bf(v.y); pk.u[2] = f2bf(v.z); pk.u[3] = f2bf(v.w);
      *(uint2*)&S[row * 136 + off4 * 4] = pk.d;
    }
    __syncthreads();

    floatx4 acc1[4][4];
    #pragma unroll
    for (int rt = 0; rt < 4; ++rt)
      #pragma unroll
      for (int c = 0; c < 4; ++c) acc1[rt][c] = (floatx4)0.f;

    #pragma unroll
    for (int s = 0; s < 4; ++s) {
      short8 av[4];
      #pragma unroll
      for (int rt = 0; rt < 4; ++rt)
        av[rt] = *(const short8*)&S[(rt * 16 + l15) * 136 + s * 32 + quad * 8];
      #pragma unroll
      for (int c = 0; c < 4; ++c) {
        short8 bv = *(const short8*)&W1s[((s * 16 + wv * 4 + c) * 64 + lane) * 8];
        #pragma unroll
        for (int rt = 0; rt < 4; ++rt)
          acc1[rt][c] = __builtin_amdgcn_mfma_f32_16x16x32_bf16(av[rt], bv, acc1[rt][c], 0, 0, 0);
      }
    }
    __syncthreads();

    #pragma unroll
    for (int c = 0; c < 4; ++c) {
      int col = (wv * 4 + c) * 16 + l15;
      float bb = b1[col];
      #pragma unroll
      for (int rt = 0; rt < 4; ++rt)
        #pragma unroll
        for (int reg = 0; reg < 4; ++reg)
          S[(rt * 16 + quad * 4 + reg) * 264 + col] = f2bf(fmaxf(acc1[rt][c][reg] + bb, 0.f));
    }
    __syncthreads();

    floatx4 acc2[4];
    #pragma unroll
    for (int c = 0; c < 4; ++c) acc2[c] = (floatx4)0.f;
    #pragma unroll
    for (int s = 0; s < 8; ++s) {
      short8 av = *(const short8*)&S[(wv * 16 + l15) * 264 + s * 32 + quad * 8];
      #pragma unroll
      for (int c = 0; c < 4; ++c) {
        short8 bv = *(const short8*)&W2s[((s * 4 + c) * 64 + lane) * 8];
        acc2[c] = __builtin_amdgcn_mfma_f32_16x16x32_bf16(av, bv, acc2[c], 0, 0, 0);
      }
    }
    __syncthreads();

    #pragma unroll
    for (int c = 0; c < 4; ++c) {
      int col = c * 16 + l15;
      float bb = b2[c * 16 + l15];
      #pragma unroll
      for (int reg = 0; reg < 4; ++reg)
        S[(wv * 16 + quad * 4 + reg) * 72 + col] = f2bf(acc2[c][reg] + bb);
    }
    __syncthreads();

    #pragma unroll
    for (int it = 0; it < 2; ++it) {
      int idx = it * 256 + t;
      int row = idx >> 3, ch = idx & 7;
      int node = nb + row;
      if (node < NN) {
        short8 v = *(const short8*)&S[row * 72 + ch * 8];
        *(short8*)&mh[(size_t)node * 64 + ch * 8] = v;
        *(uint2*)&h8[(size_t)node * 64 + ch * 8] = bf8_to_fp8x8(v);
      }
    }
  } else {
    // ---------------- BIN ----------------
    unsigned (*bin)[QCAPB] = (unsigned (*)[QCAPB])U;            // 25600 B
    unsigned* lcur = (unsigned*)(U + NQ * QCAPB * 4);           // +800 B
    int bid = blockIdx.x - NGEMM;
    int shard = bid & 7;
    for (int i = t; i < NQ; i += 256) lcur[i] = 0;
    __syncthreads();
    int base = bid * SLICE;

    unsigned rec[8];
    int qq[8];
    unsigned idx[8];
    #pragma unroll
    for (int it = 0; it < 8; ++it) {
      int e = base + it * 256 + t;
      qq[it] = -1;
      if (e < NE) {
        int d = __builtin_nontemporal_load(&dst[e]);
        int s = __builtin_nontemporal_load(&src[e]);
        int tv = __builtin_nontemporal_load(&etype[e]);
        int q = d / SUBN;
        int local = d - q * SUBN;
        rec[it] = ((unsigned)local << 20) | (unsigned)(s | (tv << 17));
        qq[it] = q;
        unsigned i = atomicAdd(&lcur[q], 1u);
        idx[it] = i;
        if (i < QCAPB) bin[q][i] = rec[it];
      }
    }
    __syncthreads();
    // flush: one thread per queue -> one tail atomic + contiguous copy
    if (t < NQ) {
      unsigned c = min(lcur[t], (unsigned)QCAPB);
      if (c) {
        unsigned gb = atomicAdd(&gtail[(t * NSH + shard) * 16], c);
        unsigned* qst = staging + (size_t)(t * NSH + shard) * SQS + gb;
        const unsigned* b = bin[t];
        for (unsigned i = 0; i < c; ++i) qst[i] = b[i];
      }
    }
    // overflow stragglers (probability ~1e-3 per grid; correctness fallback)
    #pragma unroll
    for (int it = 0; it < 8; ++it) {
      if (qq[it] >= 0 && idx[it] >= QCAPB) {
        unsigned gb = atomicAdd(&gtail[(qq[it] * NSH + shard) * 16], 1u);
        staging[(size_t)(qq[it] * NSH + shard) * SQS + gb] = rec[it];
      }
    }
  }
}

// ---------------- scatter: exclusive 500-node ownership ----------------

__launch_bounds__(512)
__global__ void scatter_kernel(const unsigned* __restrict__ staging,
                               const unsigned* __restrict__ gtail,
                               unsigned* __restrict__ cpack, int* __restrict__ csr) {
  __shared__ int cnt[SUBN];
  int t = threadIdx.x;
  int q = blockIdx.x;
  int n0 = q * SUBN;
  for (int i = t; i < SUBN; i += 512) cnt[i] = 0;
  __syncthreads();

  #pragma unroll 1
  for (int sh = 0; sh < NSH; ++sh) {
    unsigned n = gtail[(q * NSH + sh) * 16];
    const unsigned* st = staging + (size_t)(q * NSH + sh) * SQS;
    for (unsigned i = t; i < n; i += 512) {
      unsigned r = st[i];
      int local = r >> 20;
      int rank = atomicAdd(&cnt[local], 1);
      csr[(n0 + local) * CAP + rank] = (int)(r & 0xFFFFF);
    }
  }
  __syncthreads();

  if (t < SUBN / 4) {
    unsigned w = (unsigned)cnt[t * 4] | ((unsigned)cnt[t * 4 + 1] << 8) |
                 ((unsigned)cnt[t * 4 + 2] << 16) | ((unsigned)cnt[t * 4 + 3] << 24);
    cpack[(n0 >> 2) + t] = w;
  }
}

// ---------------- fused aggregation + GRU, 256 threads / 32 nodes ----------------
// Gather: batches of 12 edges, csr row read via 3x 16B nontemporal loads
// (contiguous, 16B-aligned). LAST=true: skip outputs, fuse pooling.

template <bool LAST>
__launch_bounds__(256, 8)
__global__ void agru_kernel(const ushort_t* __restrict__ mhin,
                            const unsigned char* __restrict__ h8in,
                            const unsigned* __restrict__ cpack,
                            const int* __restrict__ csr, const float* __restrict__ wtab,
                            const ushort_t* __restrict__ Wcs,
                            const float* __restrict__ b_ih, const float* __restrict__ b_hh,
                            ushort_t* __restrict__ mhout, unsigned char* __restrict__ h8out,
                            const unsigned char* __restrict__ flagb,
                            float* __restrict__ pooled) {
  __shared__ ushort_t As[32 * 136];   // 8704 B
  __shared__ ushort_t Os[32 * 72];    // 4608 B
  __shared__ float wt[16];
  __shared__ float red[132];
  int t = threadIdx.x;
  int nb = blockIdx.x * 32;
  if (t < 16) wt[t] = (t < 8) ? wtab[t] : 0.f;
  if (LAST) { for (int i = t; i < 132; i += 256) red[i] = 0.f; }
  __syncthreads();   // wt/red visible; no memory ops pending

  int g8 = t >> 3, lane8 = t & 7;
  int node = nb + g8;

  // issue h load (consumed only after agg -> latency hidden)
  short8 hreg = *(const short8*)&mhin[(size_t)node * 64 + lane8 * 8];

  // aggregation: one row per 8-lane group, batches of 12 (3x 16B csr loads)
  int deg = (cpack[node >> 2] >> ((node & 3) * 8)) & 255;
  const intx4* crow = (const intx4*)(csr + (size_t)node * CAP);
  float f0 = 0.f, f1 = 0.f, f2 = 0.f, f3 = 0.f;
  float f4 = 0.f, f5 = 0.f, f6 = 0.f, f7 = 0.f;
  for (int p = 0; p < deg; p += 12) {
    intx4 k4[3];
    #pragma unroll
    for (int c = 0; c < 3; ++c)
      k4[c] = __builtin_nontemporal_load(&crow[(p >> 2) + c]);
    int k[12];
    #pragma unroll
    for (int c = 0; c < 3; ++c) {
      k[c * 4 + 0] = k4[c][0]; k[c * 4 + 1] = k4[c][1];
      k[c * 4 + 2] = k4[c][2]; k[c * 4 + 3] = k4[c][3];
    }
    #pragma unroll
    for (int i = 0; i < 12; ++i)
      if (p + i >= deg) k[i] = (8 << 17);   // sentinel: wt=0, src=0
    uint2 v[12];
    #pragma unroll
    for (int i = 0; i < 12; ++i)
      v[i] = *(const uint2*)&h8in[(size_t)(k[i] & 0x1FFFF) * 64 + lane8 * 8];
    #pragma unroll
    for (int i = 0; i < 12; ++i) {
      float w = wt[k[i] >> 17];
      floatx2 xlo = __builtin_amdgcn_cvt_pk_f32_fp8((int)v[i].x, false);
      floatx2 xhi = __builtin_amdgcn_cvt_pk_f32_fp8((int)v[i].x, true);
      floatx2 ylo = __builtin_amdgcn_cvt_pk_f32_fp8((int)v[i].y, false);
      floatx2 yhi = __builtin_amdgcn_cvt_pk_f32_fp8((int)v[i].y, true);
      f0 += w * xlo[0]; f1 += w * xlo[1]; f2 += w * xhi[0]; f3 += w * xhi[1];
      f4 += w * ylo[0]; f5 += w * ylo[1]; f6 += w * yhi[0]; f7 += w * yhi[1];
    }
  }
  {
    float invd = 1.f / fmaxf((float)deg, 1.f);
    short8 pk;
    pk[0] = (short)f2bf(f0 * invd); pk[1] = (short)f2bf(f1 * invd);
    pk[2] = (short)f2bf(f2 * invd); pk[3] = (short)f2bf(f3 * invd);
    pk[4] = (short)f2bf(f4 * invd); pk[5] = (short)f2bf(f5 * invd);
    pk[6] = (short)f2bf(f6 * invd); pk[7] = (short)f2bf(f7 * invd);
    *(short8*)&As[g8 * 136 + lane8 * 8] = pk;
    *(short8*)&As[g8 * 136 + 64 + lane8 * 8] = hreg;
  }
  __syncthreads();

  // GEMM: [32 nodes x 128] @ Wcs[128 x 256]; wave wv = col-quarter
  int wv = t >> 6, lane = t & 63;
  int quad = lane >> 4, l15 = lane & 15;

  floatx4 acc[2][4];
  #pragma unroll
  for (int rt = 0; rt < 2; ++rt)
    #pragma unroll
    for (int g = 0; g < 4; ++g) acc[rt][g] = (floatx4)0.f;

  #pragma unroll
  for (int s4 = 0; s4 < 4; ++s4) {
    short8 av[2];
    #pragma unroll
    for (int rt = 0; rt < 2; ++rt)
      av[rt] = *(const short8*)&As[(rt * 16 + l15) * 136 + s4 * 32 + quad * 8];
    #pragma unroll
    for (int g = 0; g < 4; ++g) {
      short8 bv = *(const short8*)&Wcs[((s4 * 16 + g * 4 + wv) * 64 + lane) * 8];
      #pragma unroll
      for (int rt = 0; rt < 2; ++rt)
        acc[rt][g] = __builtin_amdgcn_mfma_f32_16x16x32_bf16(av[rt], bv, acc[rt][g], 0, 0, 0);
    }
  }

  int j = wv * 16 + l15;
  float bir = b_ih[j] + b_hh[j];
  float biz = b_ih[64 + j] + b_hh[64 + j];
  float bin_ = b_ih[128 + j];
  float bhn = b_hh[128 + j];

  if (!LAST) {
    #pragma unroll
    for (int rt = 0; rt < 2; ++rt) {
      #pragma unroll
      for (int reg = 0; reg < 4; ++reg) {
        int lrow = rt * 16 + quad * 4 + reg;
        float r = sigmoidf_(acc[rt][0][reg] + bir);
        float z = sigmoidf_(acc[rt][1][reg] + biz);
        float n = tanhf_fast(acc[rt][2][reg] + bin_ + r * (acc[rt][3][reg] + bhn));
        float hp = bf2f(As[lrow * 136 + 64 + j]);
        Os[lrow * 72 + j] = f2bf((1.f - z) * n + z * hp);
      }
    }
    __syncthreads();
    short8 vo = *(const short8*)&Os[g8 * 72 + lane8 * 8];
    *(short8*)&mhout[(size_t)node * 64 + lane8 * 8] = vo;
    *(uint2*)&h8out[(size_t)node * 64 + lane8 * 8] = bf8_to_fp8x8(vo);
  } else {
    // pool partials in registers: channel j, 8 rows per thread
    float psum = 0.f, fsum = 0.f;
    #pragma unroll
    for (int rt = 0; rt < 2; ++rt) {
      #pragma unroll
      for (int reg = 0; reg < 4; ++reg) {
        int lrow = rt * 16 + quad * 4 + reg;
        float r = sigmoidf_(acc[rt][0][reg] + bir);
        float z = sigmoidf_(acc[rt][1][reg] + biz);
        float n = tanhf_fast(acc[rt][2][reg] + bin_ + r * (acc[rt][3][reg] + bhn));
        float hp = bf2f(As[lrow * 136 + 64 + j]);
        float hn = (1.f - z) * n + z * hp;
        psum += hn;
        if (flagb[nb + lrow]) fsum += hn;
      }
    }
    atomicAdd(&red[j], psum);          // 4-way LDS contention (quad)
    atomicAdd(&red[64 + j], fsum);
    if (t < 32) { if (flagb[nb + t]) atomicAdd(&red[128], 1.f); }
    __syncthreads();
    if (t < 129) atomicAdd(&pooled[(blockIdx.x & (NSPLAY - 1)) * PSTRIDE + t], red[t]);
  }
}

// ---------------- head (folds 32 splayed pool copies) ----------------

__global__ void final_kernel(const float* __restrict__ pooled,
                             const float* __restrict__ fc1_w, const float* __restrict__ fc1_b,
                             const float* __restrict__ fc2_w, const float* __restrict__ fc2_b,
                             const float* __restrict__ w_imp, float* __restrict__ out) {
  __shared__ float p[64];
  __shared__ float hid[256];
  __shared__ float o[2];
  __shared__ float cnt_s;
  int t = threadIdx.x;
  float wpos = softplusf_(w_imp[0]);
  float b = 0.f, f = 0.f;
  if (t < 64) {
    #pragma unroll 4
    for (int k = 0; k < NSPLAY; ++k) {
      b += pooled[k * PSTRIDE + t];
      f += pooled[k * PSTRIDE + 64 + t];
    }
  }
  if (t == 64) {
    float c = 0.f;
    for (int k = 0; k < NSPLAY; ++k) c += pooled[k * PSTRIDE + 128];
    cnt_s = c;
  }
  __syncthreads();
  if (t < 64) {
    float den = (float)NN + wpos * cnt_s;
    p[t] = (b + wpos * f) / den;
  }
  __syncthreads();
  {
    float a = 0.f;
    for (int k = 0; k < 64; ++k) a += p[k] * fc1_w[t * 64 + k];
    hid[t] = fmaxf(a + fc1_b[t], 0.f);
  }
  __syncthreads();
  if (t < 2) {
    float a = 0.f;
    for (int k = 0; k < 256; ++k) a += hid[k] * fc2_w[t * 256 + k];
    o[t] = a + fc2_b[t];
  }
  __syncthreads();
  if (t == 0) {
    float mx = fmaxf(o[0], o[1]);
    float lse = mx + logf(__expf(o[0] - mx) + __expf(o[1] - mx));
    out[0] = o[0] - lse;
    out[1] = o[1] - lse;
  }
}

// ---------------- launch ----------------

extern "C" void kernel_launch(void* const* d_in, const int* in_sizes, int n_in,
                              void* d_out, int out_size, void* d_ws, size_t ws_size,
                              hipStream_t stream) {
  const float* x        = (const float*)d_in[0];
  const int*   ei       = (const int*)d_in[1];
  const int*   etype    = (const int*)d_in[2];
  const int*   diff_idx = (const int*)d_in[3];
  const float* lin1_w   = (const float*)d_in[4];
  const float* lin1_b   = (const float*)d_in[5];
  const float* lin2_w   = (const float*)d_in[6];
  const float* lin2_b   = (const float*)d_in[7];
  const float* gru_w_ih = (const float*)d_in[8];
  const float* gru_w_hh = (const float*)d_in[9];
  const float* gru_b_ih = (const float*)d_in[10];
  const float* gru_b_hh = (const float*)d_in[11];
  const float* etw      = (const float*)d_in[12];
  const float* fc1_w    = (const float*)d_in[13];
  const float* fc1_b    = (const float*)d_in[14];
  const float* fc2_w    = (const float*)d_in[15];
  const float* fc2_b    = (const float*)d_in[16];
  const float* w_imp    = (const float*)d_in[17];
  float* out = (float*)d_out;

  char* ws = (char*)d_ws;
  size_t off = 0;
  auto alloc = [&](size_t bytes) -> void* {
    void* p = ws + off;
    off += (bytes + 255) & ~(size_t)255;
    return p;
  };
  ushort_t* mh0   = (ushort_t*)alloc((size_t)NN * 64 * 2);
  ushort_t* mh1   = (ushort_t*)alloc((size_t)NN * 64 * 2);
  unsigned char* h8a = (unsigned char*)alloc((size_t)NN * 64);
  unsigned char* h8b = (unsigned char*)alloc((size_t)NN * 64);
  int*   csr      = (int*)  alloc((size_t)NN * CAP * 4 + 64);   // +pad for 16B tail reads
  unsigned* staging = (unsigned*)alloc((size_t)NQ * NSH * SQS * 4);  // 6.55 MB
  ushort_t* W1s   = (ushort_t*)alloc(128 * 256 * 2);
  ushort_t* W2s   = (ushort_t*)alloc(256 * 64 * 2);
  ushort_t* Wcs   = (ushort_t*)alloc(128 * 256 * 2);
  float* wtab     = (float*)alloc(8 * 4);
  // zeroed block: gtail (1600 line-padded counters, 100KB) | cpack (NN bytes) |
  //               flag bytes (NN) | pooled (32 splayed copies x 132 floats)
  const size_t gtb = (size_t)NQ * NSH * 16 * 4;   // 102400
  const size_t plb = (size_t)NSPLAY * PSTRIDE * 4;
  char* zbase     = (char*)alloc(gtb + (size_t)NN + NN + plb);
  unsigned* gtail = (unsigned*)zbase;
  unsigned* cpack = (unsigned*)(zbase + gtb);
  unsigned char* flagb = (unsigned char*)(zbase + gtb + NN);
  float* pooled   = (float*)(zbase + gtb + NN + NN);
  const size_t zbytes = gtb + (size_t)NN + NN + plb;

  const int nagru = NN / 32;                   // 3125 exactly

  (void)hipMemsetAsync(zbase, 0, zbytes, stream);
  prep_w_kernel<<<320, 256, 0, stream>>>(lin1_w, lin2_w, gru_w_ih, gru_w_hh, etw, diff_idx,
                                         W1s, W2s, Wcs, wtab, flagb);
  binmlp_kernel<<<NGEMM + NBIN, 256, 0, stream>>>(x, W1s, lin1_b, W2s, lin2_b, mh0, h8a,
                                                  ei, ei + NE, etype, gtail, staging);
  scatter_kernel<<<NQ, 512, 0, stream>>>(staging, gtail, cpack, csr);

  agru_kernel<false><<<nagru, 256, 0, stream>>>(mh0, h8a, cpack, csr, wtab, Wcs,
                                                gru_b_ih, gru_b_hh, mh1, h8b, flagb, pooled);
  agru_kernel<false><<<nagru, 256, 0, stream>>>(mh1, h8b, cpack, csr, wtab, Wcs,
                                                gru_b_ih, gru_b_hh, mh0, h8a, flagb, pooled);
  agru_kernel<true><<<nagru, 256, 0, stream>>>(mh0, h8a, cpack, csr, wtab, Wcs,
                                               gru_b_ih, gru_b_hh, mh1, h8b, flagb, pooled);

  final_kernel<<<1, 256, 0, stream>>>(pooled, fc1_w, fc1_b, fc2_w, fc2_b, w_imp, out);
}